// Round 14
// baseline (446.401 us; speedup 1.0000x reference)
//
#include <hip/hip_runtime.h>

#define N_TOK 131072
#define KC    1024
#define DIM   256
#define GAP_THR 5e-4f
#define NBLK  (N_TOK / 128)      // 1024 token blocks

typedef __attribute__((ext_vector_type(8)))  short bf16x8;
typedef __attribute__((ext_vector_type(16))) float f32x16;

__device__ __forceinline__ unsigned short f2bf(float f) {
    unsigned int u = __float_as_uint(f);
    unsigned int r = (u + 0x7fffu + ((u >> 16) & 1u)) >> 16;   // RNE
    return (unsigned short)r;
}

// ================= ws layout =================
// 0       : cb16F (bf16)     524288 B   fragment-ordered: [g(32)][step(16)][hi*32+l31][8]
// 524288  : cnsF  (f32)        4096 B   [g(32)][hi(2)][r(16)] = -cnorm/2
// 528384  : cnorm (f32)        4096 B
// 532480  : cbT   (f32)     1048576 B   cbT[d4][code][4] transposed codebook (recheck)
// 1581056 : fcount (u32)         64 B
// 1581120 : flist (int)     4194304 B   entry = row | (blk << 17), one per pair
// 5775424 : rck   (u64)     1048576 B   per-row (dq_bits<<32 | code) atomicMin
// 6824000 : lparts (f64)       8192 B
#define WS_NEED 6832192ull

// cb -> fragment-ordered bf16 + cnsF + cbT + f64 norms (one wave per code); zeroes fcount
__global__ void vq_prep_cb(const float* __restrict__ cb, unsigned short* __restrict__ cb16F,
                           float* __restrict__ cnsF, float* __restrict__ cnorm,
                           float* __restrict__ cbT, unsigned int* __restrict__ fcount) {
    if (blockIdx.x == 0 && threadIdx.x == 0) *fcount = 0u;
    int code = blockIdx.x * 4 + (threadIdx.x >> 6);
    int lane = threadIdx.x & 63;
    float4 v = ((const float4*)cb)[(size_t)code * 64 + lane];
    ((float4*)cbT)[(size_t)lane * KC + code] = v;        // fused transpose (d4 = lane)
    ushort4 h;
    h.x = f2bf(v.x); h.y = f2bf(v.y); h.z = f2bf(v.z); h.w = f2bf(v.w);
    int d = lane * 4;
    int kb = d >> 6, ks = (d >> 4) & 3, hi = (d >> 3) & 1;
    int step = kb * 4 + ks;
    int g = code >> 5, l31 = code & 31;
    size_t sidx = ((size_t)(g * 16 + step) * 64 + hi * 32 + l31) * 8 + (d & 7);
    *(ushort4*)(cb16F + sidx) = h;           // 8 B aligned
    double s = 0.0;
    s = fma((double)v.x, (double)v.x, s);
    s = fma((double)v.y, (double)v.y, s);
    s = fma((double)v.z, (double)v.z, s);
    s = fma((double)v.w, (double)v.w, s);
    #pragma unroll
    for (int off = 32; off > 0; off >>= 1) s += __shfl_xor(s, off);
    if (lane == 0) {
        float cn = (float)s;
        cnorm[code] = cn;
        int row = code & 31;
        int hic = (row >> 2) & 1;
        int rc  = (row & 3) | ((row >> 3) << 2);
        cnsF[(g * 2 + hic) * 16 + rc] = -0.5f * cn;   // exact: acc-init = -cc/2
    }
}

// ---- Fused scores: R8's 2(code)x2(token) wave split (load:MFMA = 1:2) + DMA staging.
// Block: 4 waves = 2 wcode x 2 wtok; wave = 64 tokens (2 B-sets) x 32 codes/phase.
// 16 phases of 64 codes (32 KB LDS tile, DMA'd via global_load_lds -> no VGPR cost,
// contiguous ds_read_b128 -> no bank conflicts). cnorm enters via acc init (-cc/2).
__global__ __launch_bounds__(256)
void vq_scores_fused(const float* __restrict__ z, const unsigned short* __restrict__ cb16F,
                     const float* __restrict__ cnsF, const float* __restrict__ cb,
                     float* __restrict__ out, float* __restrict__ out_idx,
                     int* __restrict__ flist, unsigned int* __restrict__ fcount,
                     unsigned long long* __restrict__ rck, double* __restrict__ lparts)
{
    __shared__ uint4  cA[2048];         // 32 KB tile: groups {2p, 2p+1}
    __shared__ float  bm1L[2][8][128];  // 8 KB : per-wcode per-cbk per-token min
    __shared__ double sredD[4];

    const int tid  = threadIdx.x;
    const int lane = tid & 63;
    const int l31  = lane & 31;
    const int hi   = lane >> 5;
    const int wid  = tid >> 6;
    const int wcode = wid >> 1;         // 0..1 : code-subset (groups g with g&1==wcode)
    const int wtok  = wid & 1;          // 0..1 : token half
    const int tb   = blockIdx.x;

    // ---- B fragments for TWO 32-token sets + f64 zz per set ----
    bf16x8 bfr[2][4][4];
    float zzr[2];
    #pragma unroll
    for (int set = 0; set < 2; ++set) {
        const float* zr = z + (size_t)(tb * 128 + wtok * 64 + set * 32 + l31) * DIM;
        double s = 0.0;
        #pragma unroll
        for (int kb = 0; kb < 4; ++kb)
            #pragma unroll
            for (int ks = 0; ks < 4; ++ks) {
                const int d0 = kb * 64 + ks * 16 + hi * 8;
                float4 x = *(const float4*)(zr + d0);
                float4 y = *(const float4*)(zr + d0 + 4);
                s = fma((double)x.x, (double)x.x, s);
                s = fma((double)x.y, (double)x.y, s);
                s = fma((double)x.z, (double)x.z, s);
                s = fma((double)x.w, (double)x.w, s);
                s = fma((double)y.x, (double)y.x, s);
                s = fma((double)y.y, (double)y.y, s);
                s = fma((double)y.z, (double)y.z, s);
                s = fma((double)y.w, (double)y.w, s);
                bf16x8 v;
                v[0] = (short)f2bf(x.x); v[1] = (short)f2bf(x.y);
                v[2] = (short)f2bf(x.z); v[3] = (short)f2bf(x.w);
                v[4] = (short)f2bf(y.x); v[5] = (short)f2bf(y.y);
                v[6] = (short)f2bf(y.z); v[7] = (short)f2bf(y.w);
                bfr[set][kb][ks] = v;
            }
        s += __shfl_xor(s, 32);          // partner lane holds the other dim-half
        zzr[set] = (float)s;             // uniform per-row shift: argmin-invariant
    }

    // DMA stage phase p's 32 KB (groups 2p,2p+1): wave wid copies 8 KB, linear
    #define STAGE(P) do {                                                                \
        const char* gs_ = (const char*)cb16F + ((size_t)(P) << 15)                       \
                          + ((size_t)wid << 13) + (size_t)lane * 16;                     \
        char* ls_ = (char*)&cA[0] + ((size_t)wid << 13);                                 \
        _Pragma("unroll")                                                                \
        for (int i_ = 0; i_ < 8; ++i_)                                                   \
            __builtin_amdgcn_global_load_lds(                                            \
                (const __attribute__((address_space(1))) void*)(gs_ + i_ * 1024),        \
                (__attribute__((address_space(3))) void*)(ls_ + i_ * 1024), 16, 0, 0);   \
    } while (0)

    float gm1[2] = {3.0e38f, 3.0e38f}, gm2[2] = {3.0e38f, 3.0e38f};
    int   gid_[2] = {0x7fffffff, 0x7fffffff};
    float bmrun[2] = {3.0e38f, 3.0e38f};

    #pragma unroll 1
    for (int p = 0; p < 16; ++p) {
        if (p) __syncthreads();          // previous tile fully consumed
        STAGE(p);
        __syncthreads();                 // drains DMA (vmcnt 0) -> tile ready

        const int gp = 2 * p + wcode;    // this wave's group (32 codes)
        // acc init = -cc/2 (f32 exact), broadcast from cnsF
        f32x16 acc[2];
        {
            const float4* cp = (const float4*)(cnsF + ((gp * 2 + hi) << 4));
            float4 c0 = cp[0], c1 = cp[1], c2 = cp[2], c3 = cp[3];
            #pragma unroll
            for (int set = 0; set < 2; ++set) {
                acc[set][0]  = c0.x; acc[set][1]  = c0.y; acc[set][2]  = c0.z; acc[set][3]  = c0.w;
                acc[set][4]  = c1.x; acc[set][5]  = c1.y; acc[set][6]  = c1.z; acc[set][7]  = c1.w;
                acc[set][8]  = c2.x; acc[set][9]  = c2.y; acc[set][10] = c2.z; acc[set][11] = c2.w;
                acc[set][12] = c3.x; acc[set][13] = c3.y; acc[set][14] = c3.z; acc[set][15] = c3.w;
            }
        }

        const bf16x8* AF = (const bf16x8*)&cA[0];
        #pragma unroll
        for (int step = 0; step < 16; ++step) {          // k ascending (kb*4+ks)
            bf16x8 af = AF[(wcode * 16 + step) * 64 + lane];   // contiguous 1KB wave read
            acc[0] = __builtin_amdgcn_mfma_f32_32x32x16_bf16(af, bfr[0][step >> 2][step & 3], acc[0], 0, 0, 0);
            acc[1] = __builtin_amdgcn_mfma_f32_32x32x16_bf16(af, bfr[1][step >> 2][step & 3], acc[1], 0, 0, 0);
        }

        // epilogue per set: dq = fmaf(acc,-2,zz); top-2 + lowest-index over 32 codes
        #pragma unroll
        for (int set = 0; set < 2; ++set) {
            float c1v = 3.0e38f, c2v = 3.0e38f;
            #pragma unroll
            for (int r = 0; r < 16; ++r) {
                float dq = fmaf(acc[set][r], -2.0f, zzr[set]);
                acc[set][r] = dq;
                float hv = fmaxf(c1v, dq);
                c1v = fminf(c1v, dq);
                c2v = fminf(c2v, hv);                    // dup minima -> gap 0 -> flagged
            }
            int ci = 0x7fffffff;
            #pragma unroll
            for (int r = 0; r < 16; ++r) {
                int code = gp * 32 + (r & 3) + 8 * (r >> 2) + 4 * hi;
                ci = min(ci, (acc[set][r] == c1v) ? code : 0x7fffffff);
            }
            float o1 = __shfl_xor(c1v, 32);
            float o2 = __shfl_xor(c2v, 32);
            int  oi  = __shfl_xor(ci, 32);
            float nm2 = fminf(fminf(c2v, o2), fmaxf(c1v, o1));
            int  ni  = (o1 < c1v || (o1 == c1v && oi < ci)) ? oi : ci;
            float nm1 = fminf(c1v, o1);
            bmrun[set] = fminf(bmrun[set], nm1);
            if (p & 1) {                 // cbk = gp>>2 = p>>1 complete
                if (hi == 0) bm1L[wcode][p >> 1][wtok * 64 + set * 32 + l31] = bmrun[set];
                bmrun[set] = 3.0e38f;
            }
            float ng2 = fminf(fminf(gm2[set], nm2), fmaxf(gm1[set], nm1));
            if (nm1 < gm1[set] || (nm1 == gm1[set] && ni < gid_[set])) { gm1[set] = nm1; gid_[set] = ni; }
            gm2[set] = ng2;
        }
    }
    #undef STAGE

    // ---- cross-wcode merge via LDS (reuse cA space) ----
    float* sm1 = (float*)cA;             // [2][128]
    float* sm2 = sm1 + 256;
    int*   sid = (int*)(sm2 + 256);
    int*   sidF = sid + 256;             // [128] final index per token
    __syncthreads();                     // all cA reads done -> safe to reuse
    if (hi == 0) {
        #pragma unroll
        for (int set = 0; set < 2; ++set) {
            int lt = wtok * 64 + set * 32 + l31;
            sm1[wcode * 128 + lt] = gm1[set];
            sm2[wcode * 128 + lt] = gm2[set];
            sid[wcode * 128 + lt] = gid_[set];
        }
    }
    __syncthreads();
    if (tid < 128) {
        float a1 = sm1[tid],       a2 = sm2[tid];       int ai = sid[tid];
        float b1 = sm1[128 + tid], b2 = sm2[128 + tid]; int bi = sid[128 + tid];
        float m1, m2; int ix;
        if (b1 < a1 || (b1 == a1 && bi < ai)) { m1 = b1; ix = bi; m2 = fminf(b2, a1); }
        else                                   { m1 = a1; ix = ai; m2 = fminf(a2, b1); }
        sidF[tid] = ix;
        int row = tb * 128 + tid;
        out_idx[row] = (float)ix;
        float gap = m2 - m1;
        if (!(gap > GAP_THR)) {          // near-tie or NaN safety -> exact recheck
            rck[row] = ~0ull;
            #pragma unroll
            for (int c = 0; c < 8; ++c) {
                float bmin = fminf(bm1L[0][c][tid], bm1L[1][c][tid]);
                if (bmin <= m1 + GAP_THR) {
                    unsigned int pq = atomicAdd(fcount, 1u);
                    flist[pq] = row | (c << 17);
                }
            }
        }
    }
    __syncthreads();

    // ---- fused z_st + loss: wave writes rows [wid*32, wid*32+32) (z re-read L2/L3-hot) ----
    double ls = 0.0;
    #pragma unroll 4
    for (int r = 0; r < 32; ++r) {
        int idx = sidF[wid * 32 + r];                    // wave-uniform LDS broadcast
        size_t row = (size_t)tb * 128 + wid * 32 + r;
        float4 zv = ((const float4*)z)[row * 64 + lane];
        float4 cv = ((const float4*)cb)[(size_t)idx * 64 + lane];
        float4 o;
        o.x = zv.x + (cv.x - zv.x);
        o.y = zv.y + (cv.y - zv.y);
        o.z = zv.z + (cv.z - zv.z);
        o.w = zv.w + (cv.w - zv.w);
        ((float4*)out)[row * 64 + lane] = o;
        float dx = zv.x - cv.x, dy = zv.y - cv.y, dz = zv.z - cv.z, dw = zv.w - cv.w;
        ls += (double)dx * dx + (double)dy * dy + (double)dz * dz + (double)dw * dw;
    }
    #pragma unroll
    for (int off = 32; off > 0; off >>= 1) ls += __shfl_down(ls, off);
    if (lane == 0) sredD[wid] = ls;
    __syncthreads();
    if (tid == 0) lparts[tb] = (sredD[0] + sredD[1]) + (sredD[2] + sredD[3]);
}

// ---- exact np-f32-chain recheck: ONE WAVE PER (row, block) PAIR, no barriers. ----
__global__ __launch_bounds__(256)
void vq_recheck_pairs(const float* __restrict__ z, const float* __restrict__ cbT,
                      const float* __restrict__ cnorm, const int* __restrict__ flist,
                      const unsigned int* __restrict__ fcount,
                      unsigned long long* __restrict__ rck)
{
    const int tid  = threadIdx.x;
    const int wid  = tid >> 6;
    const int lane = tid & 63;
    const unsigned int cnt = *fcount;

    for (unsigned int p = blockIdx.x * 4 + wid; p < cnt; p += gridDim.x * 4) {
        const int e   = flist[p];
        const int row = e & 0x1FFFF;
        const int blk = ((unsigned int)e) >> 17;
        const float* zr = z + (size_t)row * DIM;

        float4 zv = ((const float4*)zr)[lane];
        double s = 0.0;
        s = fma((double)zv.x, (double)zv.x, s);
        s = fma((double)zv.y, (double)zv.y, s);
        s = fma((double)zv.z, (double)zv.z, s);
        s = fma((double)zv.w, (double)zv.w, s);
        #pragma unroll
        for (int off = 32; off > 0; off >>= 1) s += __shfl_xor(s, off);
        const float zz = (float)s;

        const int c0 = blk * 128 + lane;        // lane's two codes (c0 < c0+64)
        float e0 = 0.0f, e1 = 0.0f;
        #pragma unroll 8
        for (int d4 = 0; d4 < 64; ++d4) {       // strict sequential k = 0..255
            float4 zq = ((const float4*)zr)[d4];             // wave-uniform, L1-hot
            float4 a  = ((const float4*)cbT)[d4 * KC + c0];  // coalesced over lanes
            float4 b  = ((const float4*)cbT)[d4 * KC + c0 + 64];
            e0 = fmaf(zq.x, a.x, e0); e0 = fmaf(zq.y, a.y, e0);
            e0 = fmaf(zq.z, a.z, e0); e0 = fmaf(zq.w, a.w, e0);
            e1 = fmaf(zq.x, b.x, e1); e1 = fmaf(zq.y, b.y, e1);
            e1 = fmaf(zq.z, b.z, e1); e1 = fmaf(zq.w, b.w, e1);
        }
        const float dq0 = fmaf(e0, -2.0f, zz + cnorm[c0]);       // fl(fl(zz+cc) - fl(2e))
        const float dq1 = fmaf(e1, -2.0f, zz + cnorm[c0 + 64]);
        unsigned long long k0 = ((unsigned long long)__float_as_uint(dq0) << 32) | (unsigned int)c0;
        unsigned long long k1 = ((unsigned long long)__float_as_uint(dq1) << 32) | (unsigned int)(c0 + 64);
        unsigned long long k = k0 < k1 ? k0 : k1;
        #pragma unroll
        for (int off = 32; off > 0; off >>= 1) {
            unsigned long long o = __shfl_xor(k, off);
            k = o < k ? o : k;
        }
        if (lane == 0) atomicMin(&rck[row], k);
    }
}

// ---- fixup: one wave per pair (duplicates idempotent): final idx + z_st row rewrite
__global__ __launch_bounds__(256)
void vq_fixup(const float* __restrict__ z, const float* __restrict__ cb,
              const int* __restrict__ flist, const unsigned int* __restrict__ fcount,
              const unsigned long long* __restrict__ rck,
              float* __restrict__ out, float* __restrict__ out_idx)
{
    const int tid  = threadIdx.x;
    const int wid  = tid >> 6;
    const int lane = tid & 63;
    const unsigned int cnt = *fcount;

    for (unsigned int p = blockIdx.x * 4 + wid; p < cnt; p += gridDim.x * 4) {
        const int row  = flist[p] & 0x1FFFF;
        const int code = (int)(unsigned int)rck[row];   // low 32 bits = winning code
        float4 zv = ((const float4*)z)[(size_t)row * 64 + lane];
        float4 cv = ((const float4*)cb)[(size_t)code * 64 + lane];
        float4 o;
        o.x = zv.x + (cv.x - zv.x);
        o.y = zv.y + (cv.y - zv.y);
        o.z = zv.z + (cv.z - zv.z);
        o.w = zv.w + (cv.w - zv.w);
        ((float4*)out)[(size_t)row * 64 + lane] = o;
        if (lane == 0) out_idx[row] = (float)code;
    }
}

__global__ void vq_loss_final(const double* __restrict__ lparts, float* __restrict__ out_loss) {
    __shared__ double s[256];
    const int tid = threadIdx.x;
    double a = 0.0;
    for (int i = tid; i < NBLK; i += 256) a += lparts[i];
    s[tid] = a;
    __syncthreads();
    for (int sft = 128; sft > 0; sft >>= 1) {
        if (tid < sft) s[tid] += s[tid + sft];
        __syncthreads();
    }
    if (tid == 0) {
        float mean = (float)(s[0] / (double)((size_t)N_TOK * DIM));
        out_loss[0] = 0.25f * mean + mean;   // commit + codebook, reference op order
    }
}

extern "C" void kernel_launch(void* const* d_in, const int* in_sizes, int n_in,
                              void* d_out, int out_size, void* d_ws, size_t ws_size,
                              hipStream_t stream) {
    const float* z  = (const float*)d_in[0];
    const float* cb = (const float*)d_in[1];
    float* out = (float*)d_out;
    char* ws = (char*)d_ws;

    unsigned short*     cb16F  = (unsigned short*)(ws);
    float*              cnsF   = (float*)(ws + 524288);
    float*              cnorm  = (float*)(ws + 528384);
    float*              cbT    = (float*)(ws + 532480);
    unsigned int*       fcount = (unsigned int*)(ws + 1581056);
    int*                flist  = (int*)(ws + 1581120);
    unsigned long long* rck    = (unsigned long long*)(ws + 5775424);
    double*             lparts = (double*)(ws + 6824000);

    float* out_idx  = out + (size_t)N_TOK * DIM;
    float* out_loss = out_idx + N_TOK;

    vq_prep_cb<<<KC / 4, 256, 0, stream>>>(cb, cb16F, cnsF, cnorm, cbT, fcount);
    vq_scores_fused<<<NBLK, 256, 0, stream>>>(z, cb16F, cnsF, cb, out, out_idx,
                                              flist, fcount, rck, lparts);
    vq_recheck_pairs<<<1024, 256, 0, stream>>>(z, cbT, cnorm, flist, fcount, rck);
    vq_fixup<<<512, 256, 0, stream>>>(z, cb, flist, fcount, rck, out, out_idx);
    vq_loss_final<<<1, 256, 0, stream>>>(lparts, out_loss);
}

// Round 15
// 353.417 us; speedup vs baseline: 1.2631x; 1.2631x over previous
//
#include <hip/hip_runtime.h>

#define N_TOK 131072
#define KC    1024
#define DIM   256
#define GAP_THR 4e-4f
#define NBLK  (N_TOK / 128)      // 1024 token blocks

typedef __attribute__((ext_vector_type(8)))  short bf16x8;
typedef __attribute__((ext_vector_type(16))) float f32x16;

__device__ __forceinline__ unsigned short f2bf(float f) {
    unsigned int u = __float_as_uint(f);
    unsigned int r = (u + 0x7fffu + ((u >> 16) & 1u)) >> 16;   // RNE
    return (unsigned short)r;
}

// ================= ws layout =================
// 0       : cb16  (bf16)      524288 B   code-major [code][dim]
// 524288  : cnorm (f32)         4096 B
// 528384  : cbT   (f32)      1048576 B   cbT[d4][code][4] transposed codebook (recheck)
// 1576960 : fcounts (u32 x2)      64 B   [0]=fcount (rows), [1]=fcount2 (pairs)
// 1577024 : flist (int)       524288 B   entry = row | (mask << 17), one per flagged row
// 2101312 : flist2 (int)     4194304 B   entry = row | (blk << 17), one per pair
// 6295616 : rck   (u64)      1048576 B   per-row (dq_bits<<32 | code) atomicMin
// 7344192 : lparts (f64)        8192 B
#define WS_NEED 7352384ull

__global__ void vq_zero(unsigned int* p) { if (threadIdx.x < 2) p[threadIdx.x] = 0u; }

// cb -> bf16 (code-major) + f64 norms (one wave per code)   [R8-verbatim]
__global__ void vq_prep_cb(const float* __restrict__ cb, unsigned short* __restrict__ cb16,
                           float* __restrict__ cnorm) {
    int code = blockIdx.x * 4 + (threadIdx.x >> 6);
    int lane = threadIdx.x & 63;
    float4 v = ((const float4*)cb)[(size_t)code * 64 + lane];
    ushort4 h;
    h.x = f2bf(v.x); h.y = f2bf(v.y); h.z = f2bf(v.z); h.w = f2bf(v.w);
    ((ushort4*)cb16)[(size_t)code * 64 + lane] = h;
    double s = 0.0;
    s = fma((double)v.x, (double)v.x, s);
    s = fma((double)v.y, (double)v.y, s);
    s = fma((double)v.z, (double)v.z, s);
    s = fma((double)v.w, (double)v.w, s);
    #pragma unroll
    for (int off = 32; off > 0; off >>= 1) s += __shfl_xor(s, off);
    if (lane == 0) cnorm[code] = (float)s;
}

// cbT[d4][code][4] = cb[code][4*d4 .. 4*d4+4)   (for the exact recheck)
__global__ void vq_transpose(const float* __restrict__ cb, float* __restrict__ cbT) {
    int g = blockIdx.x * 256 + threadIdx.x;       // [0, 65536)
    int d4 = g >> 10, code = g & 1023;
    ((float4*)cbT)[g] = ((const float4*)cb)[(size_t)code * 64 + d4];
}

// ---- Fused: bf16 MFMA scores over ALL 1024 codes + argmin/top-2 + flagging
//      + z_st output + loss partial. One pass over z (HBM) per block.
// Block: 256 thr = 4 waves (2 wcode x 2 wtok); per wave 64 codes x 64 tokens per cbk.
// B (tokens) lives in registers for the whole kernel: bfr[f][kb][ks] bf16x8.
// A (codes) staged per cbk in 64KB swizzled LDS from L2-resident cb16.
// [VERBATIM reproduction of the R8-measured ~190us kernel — do not perturb.]
__global__ __launch_bounds__(256, 2)
void vq_scores_fused(const float* __restrict__ z, const unsigned short* __restrict__ cb16,
                     const float* __restrict__ cb, const float* __restrict__ cnorm,
                     float* __restrict__ out, float* __restrict__ out_idx,
                     int* __restrict__ flist, unsigned int* __restrict__ fcount,
                     double* __restrict__ lparts)
{
    __shared__ uint4  cA[128 * 32];     // 64 KB : 128 codes x 256 dims bf16, 16B-unit swizzled
    __shared__ float  cnsL[KC];         // 4 KB
    __shared__ float  bm1L[8][128];     // per-cbk per-token block-min
    __shared__ float  gm1[128], gm2[128];
    __shared__ int    gid[128];
    __shared__ double sredD[4];

    const int tid = threadIdx.x;
    const int lane = tid & 63;
    const int l31 = lane & 31;
    const int hi  = lane >> 5;
    const int wid = tid >> 6;
    const int wcode = wid >> 1;
    const int wtok  = wid & 1;
    const int tb = blockIdx.x;

    #pragma unroll
    for (int k = 0; k < 4; ++k) cnsL[tid + k * 256] = cnorm[tid + k * 256];
    if (tid < 128) { gm1[tid] = 3.0e38f; gm2[tid] = 3.0e38f; gid[tid] = 0x7fffffff; }

    // ---- B fragments from global f32 (lane hi-pairs consume full 64B lines) + zz ----
    bf16x8 bfr[2][4][4];
    float zzr[2];
    #pragma unroll
    for (int f = 0; f < 2; ++f) {
        const int t = tb * 128 + wtok * 64 + f * 32 + l31;
        const float* zr = z + (size_t)t * DIM;
        double s = 0.0;
        #pragma unroll
        for (int kb = 0; kb < 4; ++kb)
            #pragma unroll
            for (int ks = 0; ks < 4; ++ks) {
                const int d0 = kb * 64 + ks * 16 + hi * 8;
                float4 x = *(const float4*)(zr + d0);
                float4 y = *(const float4*)(zr + d0 + 4);
                s = fma((double)x.x, (double)x.x, s);
                s = fma((double)x.y, (double)x.y, s);
                s = fma((double)x.z, (double)x.z, s);
                s = fma((double)x.w, (double)x.w, s);
                s = fma((double)y.x, (double)y.x, s);
                s = fma((double)y.y, (double)y.y, s);
                s = fma((double)y.z, (double)y.z, s);
                s = fma((double)y.w, (double)y.w, s);
                bf16x8 v;
                v[0] = (short)f2bf(x.x); v[1] = (short)f2bf(x.y);
                v[2] = (short)f2bf(x.z); v[3] = (short)f2bf(x.w);
                v[4] = (short)f2bf(y.x); v[5] = (short)f2bf(y.y);
                v[6] = (short)f2bf(y.z); v[7] = (short)f2bf(y.w);
                bfr[f][kb][ks] = v;
            }
        s += __shfl_xor(s, 32);          // partner lane holds the other dim-half
        zzr[f] = (float)s;               // uniform per-row shift: argmin-invariant
    }

    // ---- loop all 8 code blocks ----
    #pragma unroll 1
    for (int cbk = 0; cbk < 8; ++cbk) {
        __syncthreads();                 // cA/scratch free; init visible on iter 0
        #pragma unroll
        for (int i = 0; i < 16; ++i) {   // stage 64 KB code tile, swizzled 16B units
            int g = tid + i * 256;
            int c = g >> 5, u = g & 31;
            cA[c * 32 + (u ^ (c & 7))] = ((const uint4*)cb16)[(size_t)(cbk * 128 + c) * 32 + u];
        }
        __syncthreads();

        f32x16 acc[2][2];
        #pragma unroll
        for (int a = 0; a < 2; ++a)
            #pragma unroll
            for (int b = 0; b < 2; ++b)
                #pragma unroll
                for (int r = 0; r < 16; ++r) acc[a][b][r] = 0.0f;

        #pragma unroll
        for (int kb = 0; kb < 4; ++kb)
            #pragma unroll
            for (int ks = 0; ks < 4; ++ks) {
                bf16x8 af[2];
                #pragma unroll
                for (int a = 0; a < 2; ++a) {
                    int c = wcode * 64 + a * 32 + l31;
                    af[a] = ((const bf16x8*)cA)[c * 32 + ((kb * 8 + ks * 2 + hi) ^ (c & 7))];
                }
                #pragma unroll
                for (int a = 0; a < 2; ++a)
                    #pragma unroll
                    for (int b = 0; b < 2; ++b)
                        acc[a][b] = __builtin_amdgcn_mfma_f32_32x32x16_bf16(af[a], bfr[b][kb][ks], acc[a][b], 0, 0, 0);
            }

        // epilogue: per-lane top-2 over 32 codes, lane^32 merge, stash to scratch
        float* sm1 = (float*)cA;                 // cA reusable until next stage
        float* sm2 = sm1 + 256;
        int*   sid = (int*)(sm2 + 256);
        #pragma unroll
        for (int tf = 0; tf < 2; ++tf) {
            float c1 = 3.0e38f, c2 = 3.0e38f;
            #pragma unroll
            for (int cf = 0; cf < 2; ++cf)
                #pragma unroll
                for (int r = 0; r < 16; ++r) {
                    int cl = wcode * 64 + cf * 32 + (r & 3) + 8 * (r >> 2) + 4 * hi;
                    float A  = zzr[tf] + cnsL[cbk * 128 + cl];     // fl(zz+cc)
                    float dq = fmaf(acc[cf][tf][r], -2.0f, A);     // fl(A - fl(2e))
                    acc[cf][tf][r] = dq;
                    float hv = fmaxf(c1, dq);
                    c1 = fminf(c1, dq);
                    c2 = fminf(c2, hv);
                }
            int ci = 0x7fffffff;
            #pragma unroll
            for (int cf = 0; cf < 2; ++cf)
                #pragma unroll
                for (int r = 0; r < 16; ++r) {
                    int code = cbk * 128 + wcode * 64 + cf * 32 + (r & 3) + 8 * (r >> 2) + 4 * hi;
                    ci = min(ci, (acc[cf][tf][r] == c1) ? code : 0x7fffffff);
                }
            float o1 = __shfl_xor(c1, 32);
            float o2 = __shfl_xor(c2, 32);
            int  oi = __shfl_xor(ci, 32);
            float nm2 = fminf(fminf(c2, o2), fmaxf(c1, o1));
            int  ni = (o1 < c1 || (o1 == c1 && oi < ci)) ? oi : ci;
            float nm1 = fminf(c1, o1);
            if (hi == 0) {
                int lt = wtok * 64 + tf * 32 + l31;
                sm1[wcode * 128 + lt] = nm1;
                sm2[wcode * 128 + lt] = nm2;
                sid[wcode * 128 + lt] = ni;
            }
        }
        __syncthreads();
        if (tid < 128) {                  // merge wcode halves + update running state
            float a1 = sm1[tid],       a2 = sm2[tid];       int ai = sid[tid];
            float b1 = sm1[128 + tid], b2 = sm2[128 + tid]; int bi = sid[128 + tid];
            float m1, m2; int ix;
            if (b1 < a1 || (b1 == a1 && bi < ai)) { m1 = b1; ix = bi; m2 = fminf(b2, a1); }
            else                                   { m1 = a1; ix = ai; m2 = fminf(a2, b1); }
            bm1L[cbk][tid] = m1;
            float g1 = gm1[tid], g2 = gm2[tid]; int gi = gid[tid];
            float ng2 = fminf(fminf(g2, m2), fmaxf(g1, m1));
            if (m1 < g1 || (m1 == g1 && ix < gi)) { g1 = m1; gi = ix; }
            gm1[tid] = g1; gm2[tid] = ng2; gid[tid] = gi;
        }
    }
    __syncthreads();

    // ---- flag + provisional index write (mask format; expansion happens downstream) ----
    if (tid < 128) {
        int row = tb * 128 + tid;
        out_idx[row] = (float)gid[tid];
        float g1 = gm1[tid];
        float gap = gm2[tid] - g1;
        int mask = 0;
        #pragma unroll
        for (int c = 0; c < 8; ++c) mask |= (bm1L[c][tid] <= g1 + GAP_THR) ? (1 << c) : 0;
        if (!(gap > GAP_THR)) {           // near-tie or NaN safety -> exact recheck
            unsigned int p = atomicAdd(fcount, 1u);
            flist[p] = row | (mask << 17);
        }
    }
    __syncthreads();

    // ---- fused z_st + loss (z tile re-read is L2-hot) ----
    double ls = 0.0;
    const float4* z4  = (const float4*)z;
    const float4* cb4 = (const float4*)cb;
    float4* out4 = (float4*)out;
    #pragma unroll 4
    for (int it = 0; it < 32; ++it) {
        int fi = tid + it * 256;
        int row = fi >> 6, c4 = fi & 63;
        float4 zv = z4[(size_t)(tb * 128 + row) * 64 + c4];
        int idx = gid[row];
        float4 cv = cb4[(size_t)idx * 64 + c4];
        float4 o;
        o.x = zv.x + (cv.x - zv.x);
        o.y = zv.y + (cv.y - zv.y);
        o.z = zv.z + (cv.z - zv.z);
        o.w = zv.w + (cv.w - zv.w);
        out4[(size_t)(tb * 128 + row) * 64 + c4] = o;
        float dx = zv.x - cv.x, dy = zv.y - cv.y, dz = zv.z - cv.z, dw = zv.w - cv.w;
        ls += (double)dx * dx + (double)dy * dy + (double)dz * dz + (double)dw * dw;
    }
    #pragma unroll
    for (int off = 32; off > 0; off >>= 1) ls += __shfl_down(ls, off);
    if (lane == 0) sredD[wid] = ls;
    __syncthreads();
    if (tid == 0) lparts[tb] = (sredD[0] + sredD[1]) + (sredD[2] + sredD[3]);
}

// ---- expand mask-entries into per-pair entries + seed rck (tiny) ----
__global__ void vq_expand(const int* __restrict__ flist, const unsigned int* __restrict__ fcount,
                          int* __restrict__ flist2, unsigned int* __restrict__ fcount2,
                          unsigned long long* __restrict__ rck)
{
    const unsigned int cnt = *fcount;
    for (unsigned int i = blockIdx.x * 256 + threadIdx.x; i < cnt; i += gridDim.x * 256) {
        int e = flist[i];
        int row  = e & 0x1FFFF;
        int mask = ((unsigned int)e) >> 17;
        rck[row] = ~0ull;
        while (mask) {
            int c = __ffs(mask) - 1;
            mask &= mask - 1;
            unsigned int p = atomicAdd(fcount2, 1u);
            flist2[p] = row | (c << 17);
        }
    }
}

// ---- exact np-f32-chain recheck: ONE WAVE PER (row, block) PAIR, no barriers. ----
__global__ __launch_bounds__(256)
void vq_recheck_pairs(const float* __restrict__ z, const float* __restrict__ cbT,
                      const float* __restrict__ cnorm, const int* __restrict__ flist2,
                      const unsigned int* __restrict__ fcount2,
                      unsigned long long* __restrict__ rck)
{
    const int tid  = threadIdx.x;
    const int wid  = tid >> 6;
    const int lane = tid & 63;
    const unsigned int cnt = *fcount2;

    for (unsigned int p = blockIdx.x * 4 + wid; p < cnt; p += gridDim.x * 4) {
        const int e   = flist2[p];
        const int row = e & 0x1FFFF;
        const int blk = ((unsigned int)e) >> 17;
        const float* zr = z + (size_t)row * DIM;

        float4 zv = ((const float4*)zr)[lane];
        double s = 0.0;
        s = fma((double)zv.x, (double)zv.x, s);
        s = fma((double)zv.y, (double)zv.y, s);
        s = fma((double)zv.z, (double)zv.z, s);
        s = fma((double)zv.w, (double)zv.w, s);
        #pragma unroll
        for (int off = 32; off > 0; off >>= 1) s += __shfl_xor(s, off);
        const float zz = (float)s;

        const int c0 = blk * 128 + lane;        // lane's two codes (c0 < c0+64)
        float e0 = 0.0f, e1 = 0.0f;
        #pragma unroll 8
        for (int d4 = 0; d4 < 64; ++d4) {       // strict sequential k = 0..255
            float4 zq = ((const float4*)zr)[d4];             // wave-uniform, L1-hot
            float4 a  = ((const float4*)cbT)[d4 * KC + c0];  // coalesced over lanes
            float4 b  = ((const float4*)cbT)[d4 * KC + c0 + 64];
            e0 = fmaf(zq.x, a.x, e0); e0 = fmaf(zq.y, a.y, e0);
            e0 = fmaf(zq.z, a.z, e0); e0 = fmaf(zq.w, a.w, e0);
            e1 = fmaf(zq.x, b.x, e1); e1 = fmaf(zq.y, b.y, e1);
            e1 = fmaf(zq.z, b.z, e1); e1 = fmaf(zq.w, b.w, e1);
        }
        const float dq0 = fmaf(e0, -2.0f, zz + cnorm[c0]);       // fl(fl(zz+cc) - fl(2e))
        const float dq1 = fmaf(e1, -2.0f, zz + cnorm[c0 + 64]);
        unsigned long long k0 = ((unsigned long long)__float_as_uint(dq0) << 32) | (unsigned int)c0;
        unsigned long long k1 = ((unsigned long long)__float_as_uint(dq1) << 32) | (unsigned int)(c0 + 64);
        unsigned long long k = k0 < k1 ? k0 : k1;
        #pragma unroll
        for (int off = 32; off > 0; off >>= 1) {
            unsigned long long o = __shfl_xor(k, off);
            k = o < k ? o : k;
        }
        if (lane == 0) atomicMin(&rck[row], k);
    }
}

// ---- fixup: one wave per pair (duplicates idempotent): final idx + z_st row rewrite
__global__ __launch_bounds__(256)
void vq_fixup(const float* __restrict__ z, const float* __restrict__ cb,
              const int* __restrict__ flist2, const unsigned int* __restrict__ fcount2,
              const unsigned long long* __restrict__ rck,
              float* __restrict__ out, float* __restrict__ out_idx)
{
    const int tid  = threadIdx.x;
    const int wid  = tid >> 6;
    const int lane = tid & 63;
    const unsigned int cnt = *fcount2;

    for (unsigned int p = blockIdx.x * 4 + wid; p < cnt; p += gridDim.x * 4) {
        const int row  = flist2[p] & 0x1FFFF;
        const int code = (int)(unsigned int)rck[row];   // low 32 bits = winning code
        float4 zv = ((const float4*)z)[(size_t)row * 64 + lane];
        float4 cv = ((const float4*)cb)[(size_t)code * 64 + lane];
        float4 o;
        o.x = zv.x + (cv.x - zv.x);
        o.y = zv.y + (cv.y - zv.y);
        o.z = zv.z + (cv.z - zv.z);
        o.w = zv.w + (cv.w - zv.w);
        ((float4*)out)[(size_t)row * 64 + lane] = o;
        if (lane == 0) out_idx[row] = (float)code;
    }
}

__global__ void vq_loss_final(const double* __restrict__ lparts, float* __restrict__ out_loss) {
    __shared__ double s[256];
    const int tid = threadIdx.x;
    double a = 0.0;
    for (int i = tid; i < NBLK; i += 256) a += lparts[i];
    s[tid] = a;
    __syncthreads();
    for (int sft = 128; sft > 0; sft >>= 1) {
        if (tid < sft) s[tid] += s[tid + sft];
        __syncthreads();
    }
    if (tid == 0) {
        float mean = (float)(s[0] / (double)((size_t)N_TOK * DIM));
        out_loss[0] = 0.25f * mean + mean;   // commit + codebook, reference op order
    }
}

extern "C" void kernel_launch(void* const* d_in, const int* in_sizes, int n_in,
                              void* d_out, int out_size, void* d_ws, size_t ws_size,
                              hipStream_t stream) {
    const float* z  = (const float*)d_in[0];
    const float* cb = (const float*)d_in[1];
    float* out = (float*)d_out;
    char* ws = (char*)d_ws;

    unsigned short*     cb16    = (unsigned short*)(ws);
    float*              cnorm   = (float*)(ws + 524288);
    float*              cbT     = (float*)(ws + 528384);
    unsigned int*       fcounts = (unsigned int*)(ws + 1576960);   // [0]=rows, [1]=pairs
    int*                flist   = (int*)(ws + 1577024);
    int*                flist2  = (int*)(ws + 2101312);
    unsigned long long* rck     = (unsigned long long*)(ws + 6295616);
    double*             lparts  = (double*)(ws + 7344192);

    float* out_idx  = out + (size_t)N_TOK * DIM;
    float* out_loss = out_idx + N_TOK;

    vq_zero<<<1, 64, 0, stream>>>(fcounts);
    vq_prep_cb<<<KC / 4, 256, 0, stream>>>(cb, cb16, cnorm);
    vq_transpose<<<(KC * DIM / 4) / 256, 256, 0, stream>>>(cb, cbT);
    vq_scores_fused<<<NBLK, 256, 0, stream>>>(z, cb16, cb, cnorm, out, out_idx,
                                              flist, fcounts, lparts);
    vq_expand<<<64, 256, 0, stream>>>(flist, fcounts, flist2, fcounts + 1, rck);
    vq_recheck_pairs<<<1024, 256, 0, stream>>>(z, cbT, cnorm, flist2, fcounts + 1, rck);
    vq_fixup<<<512, 256, 0, stream>>>(z, cb, flist2, fcounts + 1, rck, out, out_idx);
    vq_loss_final<<<1, 256, 0, stream>>>(lparts, out_loss);
}

// Round 16
// 326.701 us; speedup vs baseline: 1.3664x; 1.0818x over previous
//
#include <hip/hip_runtime.h>

#define N_TOK 131072
#define KC    1024
#define DIM   256
#define GAP_THR 4e-4f
#define NBLK  (N_TOK / 128)      // 1024 token blocks

typedef __attribute__((ext_vector_type(8)))  short bf16x8;
typedef __attribute__((ext_vector_type(16))) float f32x16;

__device__ __forceinline__ unsigned short f2bf(float f) {
    unsigned int u = __float_as_uint(f);
    unsigned int r = (u + 0x7fffu + ((u >> 16) & 1u)) >> 16;   // RNE
    return (unsigned short)r;
}

// ================= ws layout =================
// 0       : cb16  (bf16)      524288 B   code-major [code][dim]
// 524288  : cnorm (f32)         4096 B
// 528384  : cbT   (f32)      1048576 B   cbT[d4][code][4] transposed codebook (recheck)
// 1576960 : fcounts (u32 x2)      64 B   [0]=fcount (rows), [1]=fcount2 (pairs)
// 1577024 : flist (int)       524288 B   entry = row | (mask << 17), one per flagged row
// 2101312 : flist2 (int)     4194304 B   entry = row | (blk << 17), one per pair
// 6295616 : rck   (u64)      1048576 B   per-row (dq_bits<<32 | code) atomicMin
// 7344192 : lparts (f64)        8192 B
#define WS_NEED 7352384ull

// cb -> bf16 (code-major) + cbT (fused transpose, d4 = lane) + f64 norms; zeroes counters
__global__ void vq_prep_cb(const float* __restrict__ cb, unsigned short* __restrict__ cb16,
                           float* __restrict__ cnorm, float* __restrict__ cbT,
                           unsigned int* __restrict__ fcounts) {
    if (blockIdx.x == 0 && threadIdx.x < 2) fcounts[threadIdx.x] = 0u;
    int code = blockIdx.x * 4 + (threadIdx.x >> 6);
    int lane = threadIdx.x & 63;
    float4 v = ((const float4*)cb)[(size_t)code * 64 + lane];
    ((float4*)cbT)[(size_t)lane * KC + code] = v;        // fused transpose
    ushort4 h;
    h.x = f2bf(v.x); h.y = f2bf(v.y); h.z = f2bf(v.z); h.w = f2bf(v.w);
    ((ushort4*)cb16)[(size_t)code * 64 + lane] = h;
    double s = 0.0;
    s = fma((double)v.x, (double)v.x, s);
    s = fma((double)v.y, (double)v.y, s);
    s = fma((double)v.z, (double)v.z, s);
    s = fma((double)v.w, (double)v.w, s);
    #pragma unroll
    for (int off = 32; off > 0; off >>= 1) s += __shfl_xor(s, off);
    if (lane == 0) cnorm[code] = (float)s;
}

// ---- Fused: bf16 MFMA scores over ALL 1024 codes + argmin/top-2 + flagging
//      + z_st output + loss partial. One pass over z (HBM) per block.
// Block: 256 thr = 4 waves (2 wcode x 2 wtok); per wave 64 codes x 64 tokens per cbk.
// B (tokens) lives in registers for the whole kernel: bfr[f][kb][ks] bf16x8.
// A (codes) staged per cbk in 64KB swizzled LDS from L2-resident cb16.
// [Body identical to the R8/R15-passing kernel; ONLY the launch bound changed:
//  (256,2) capped arch regs at 256 and the compiler's VGPR/AGPR split (128/128)
//  spilled bfr (87 MB scratch HBM traffic, R15). Plain (256) lets it allocate
//  ~220 regs -> no spill; 512/220 still = 2 waves/SIMD.]
__global__ __launch_bounds__(256)
void vq_scores_fused(const float* __restrict__ z, const unsigned short* __restrict__ cb16,
                     const float* __restrict__ cb, const float* __restrict__ cnorm,
                     float* __restrict__ out, float* __restrict__ out_idx,
                     int* __restrict__ flist, unsigned int* __restrict__ fcount,
                     double* __restrict__ lparts)
{
    __shared__ uint4  cA[128 * 32];     // 64 KB : 128 codes x 256 dims bf16, 16B-unit swizzled
    __shared__ float  cnsL[KC];         // 4 KB
    __shared__ float  bm1L[8][128];     // per-cbk per-token block-min
    __shared__ float  gm1[128], gm2[128];
    __shared__ int    gid[128];
    __shared__ double sredD[4];

    const int tid = threadIdx.x;
    const int lane = tid & 63;
    const int l31 = lane & 31;
    const int hi  = lane >> 5;
    const int wid = tid >> 6;
    const int wcode = wid >> 1;
    const int wtok  = wid & 1;
    const int tb = blockIdx.x;

    #pragma unroll
    for (int k = 0; k < 4; ++k) cnsL[tid + k * 256] = cnorm[tid + k * 256];
    if (tid < 128) { gm1[tid] = 3.0e38f; gm2[tid] = 3.0e38f; gid[tid] = 0x7fffffff; }

    // ---- B fragments from global f32 (lane hi-pairs consume full 64B lines) + zz ----
    bf16x8 bfr[2][4][4];
    float zzr[2];
    #pragma unroll
    for (int f = 0; f < 2; ++f) {
        const int t = tb * 128 + wtok * 64 + f * 32 + l31;
        const float* zr = z + (size_t)t * DIM;
        double s = 0.0;
        #pragma unroll
        for (int kb = 0; kb < 4; ++kb)
            #pragma unroll
            for (int ks = 0; ks < 4; ++ks) {
                const int d0 = kb * 64 + ks * 16 + hi * 8;
                float4 x = *(const float4*)(zr + d0);
                float4 y = *(const float4*)(zr + d0 + 4);
                s = fma((double)x.x, (double)x.x, s);
                s = fma((double)x.y, (double)x.y, s);
                s = fma((double)x.z, (double)x.z, s);
                s = fma((double)x.w, (double)x.w, s);
                s = fma((double)y.x, (double)y.x, s);
                s = fma((double)y.y, (double)y.y, s);
                s = fma((double)y.z, (double)y.z, s);
                s = fma((double)y.w, (double)y.w, s);
                bf16x8 v;
                v[0] = (short)f2bf(x.x); v[1] = (short)f2bf(x.y);
                v[2] = (short)f2bf(x.z); v[3] = (short)f2bf(x.w);
                v[4] = (short)f2bf(y.x); v[5] = (short)f2bf(y.y);
                v[6] = (short)f2bf(y.z); v[7] = (short)f2bf(y.w);
                bfr[f][kb][ks] = v;
            }
        s += __shfl_xor(s, 32);          // partner lane holds the other dim-half
        zzr[f] = (float)s;               // uniform per-row shift: argmin-invariant
    }

    // ---- loop all 8 code blocks ----
    #pragma unroll 1
    for (int cbk = 0; cbk < 8; ++cbk) {
        __syncthreads();                 // cA/scratch free; init visible on iter 0
        #pragma unroll
        for (int i = 0; i < 16; ++i) {   // stage 64 KB code tile, swizzled 16B units
            int g = tid + i * 256;
            int c = g >> 5, u = g & 31;
            cA[c * 32 + (u ^ (c & 7))] = ((const uint4*)cb16)[(size_t)(cbk * 128 + c) * 32 + u];
        }
        __syncthreads();

        f32x16 acc[2][2];
        #pragma unroll
        for (int a = 0; a < 2; ++a)
            #pragma unroll
            for (int b = 0; b < 2; ++b)
                #pragma unroll
                for (int r = 0; r < 16; ++r) acc[a][b][r] = 0.0f;

        #pragma unroll
        for (int kb = 0; kb < 4; ++kb)
            #pragma unroll
            for (int ks = 0; ks < 4; ++ks) {
                bf16x8 af[2];
                #pragma unroll
                for (int a = 0; a < 2; ++a) {
                    int c = wcode * 64 + a * 32 + l31;
                    af[a] = ((const bf16x8*)cA)[c * 32 + ((kb * 8 + ks * 2 + hi) ^ (c & 7))];
                }
                #pragma unroll
                for (int a = 0; a < 2; ++a)
                    #pragma unroll
                    for (int b = 0; b < 2; ++b)
                        acc[a][b] = __builtin_amdgcn_mfma_f32_32x32x16_bf16(af[a], bfr[b][kb][ks], acc[a][b], 0, 0, 0);
            }

        // epilogue: per-lane top-2 over 32 codes, lane^32 merge, stash to scratch
        float* sm1 = (float*)cA;                 // cA reusable until next stage
        float* sm2 = sm1 + 256;
        int*   sid = (int*)(sm2 + 256);
        #pragma unroll
        for (int tf = 0; tf < 2; ++tf) {
            float c1 = 3.0e38f, c2 = 3.0e38f;
            #pragma unroll
            for (int cf = 0; cf < 2; ++cf)
                #pragma unroll
                for (int r = 0; r < 16; ++r) {
                    int cl = wcode * 64 + cf * 32 + (r & 3) + 8 * (r >> 2) + 4 * hi;
                    float A  = zzr[tf] + cnsL[cbk * 128 + cl];     // fl(zz+cc)
                    float dq = fmaf(acc[cf][tf][r], -2.0f, A);     // fl(A - fl(2e))
                    acc[cf][tf][r] = dq;
                    float hv = fmaxf(c1, dq);
                    c1 = fminf(c1, dq);
                    c2 = fminf(c2, hv);
                }
            int ci = 0x7fffffff;
            #pragma unroll
            for (int cf = 0; cf < 2; ++cf)
                #pragma unroll
                for (int r = 0; r < 16; ++r) {
                    int code = cbk * 128 + wcode * 64 + cf * 32 + (r & 3) + 8 * (r >> 2) + 4 * hi;
                    ci = min(ci, (acc[cf][tf][r] == c1) ? code : 0x7fffffff);
                }
            float o1 = __shfl_xor(c1, 32);
            float o2 = __shfl_xor(c2, 32);
            int  oi = __shfl_xor(ci, 32);
            float nm2 = fminf(fminf(c2, o2), fmaxf(c1, o1));
            int  ni = (o1 < c1 || (o1 == c1 && oi < ci)) ? oi : ci;
            float nm1 = fminf(c1, o1);
            if (hi == 0) {
                int lt = wtok * 64 + tf * 32 + l31;
                sm1[wcode * 128 + lt] = nm1;
                sm2[wcode * 128 + lt] = nm2;
                sid[wcode * 128 + lt] = ni;
            }
        }
        __syncthreads();
        if (tid < 128) {                  // merge wcode halves + update running state
            float a1 = sm1[tid],       a2 = sm2[tid];       int ai = sid[tid];
            float b1 = sm1[128 + tid], b2 = sm2[128 + tid]; int bi = sid[128 + tid];
            float m1, m2; int ix;
            if (b1 < a1 || (b1 == a1 && bi < ai)) { m1 = b1; ix = bi; m2 = fminf(b2, a1); }
            else                                   { m1 = a1; ix = ai; m2 = fminf(a2, b1); }
            bm1L[cbk][tid] = m1;
            float g1 = gm1[tid], g2 = gm2[tid]; int gi = gid[tid];
            float ng2 = fminf(fminf(g2, m2), fmaxf(g1, m1));
            if (m1 < g1 || (m1 == g1 && ix < gi)) { g1 = m1; gi = ix; }
            gm1[tid] = g1; gm2[tid] = ng2; gid[tid] = gi;
        }
    }
    __syncthreads();

    // ---- flag + provisional index write (mask format; expansion happens downstream) ----
    if (tid < 128) {
        int row = tb * 128 + tid;
        out_idx[row] = (float)gid[tid];
        float g1 = gm1[tid];
        float gap = gm2[tid] - g1;
        int mask = 0;
        #pragma unroll
        for (int c = 0; c < 8; ++c) mask |= (bm1L[c][tid] <= g1 + GAP_THR) ? (1 << c) : 0;
        if (!(gap > GAP_THR)) {           // near-tie or NaN safety -> exact recheck
            unsigned int p = atomicAdd(fcount, 1u);
            flist[p] = row | (mask << 17);
        }
    }
    __syncthreads();

    // ---- fused z_st + loss (z tile re-read is L2-hot) ----
    double ls = 0.0;
    const float4* z4  = (const float4*)z;
    const float4* cb4 = (const float4*)cb;
    float4* out4 = (float4*)out;
    #pragma unroll 4
    for (int it = 0; it < 32; ++it) {
        int fi = tid + it * 256;
        int row = fi >> 6, c4 = fi & 63;
        float4 zv = z4[(size_t)(tb * 128 + row) * 64 + c4];
        int idx = gid[row];
        float4 cv = cb4[(size_t)idx * 64 + c4];
        float4 o;
        o.x = zv.x + (cv.x - zv.x);
        o.y = zv.y + (cv.y - zv.y);
        o.z = zv.z + (cv.z - zv.z);
        o.w = zv.w + (cv.w - zv.w);
        out4[(size_t)(tb * 128 + row) * 64 + c4] = o;
        float dx = zv.x - cv.x, dy = zv.y - cv.y, dz = zv.z - cv.z, dw = zv.w - cv.w;
        ls += (double)dx * dx + (double)dy * dy + (double)dz * dz + (double)dw * dw;
    }
    #pragma unroll
    for (int off = 32; off > 0; off >>= 1) ls += __shfl_down(ls, off);
    if (lane == 0) sredD[wid] = ls;
    __syncthreads();
    if (tid == 0) lparts[tb] = (sredD[0] + sredD[1]) + (sredD[2] + sredD[3]);
}

// ---- expand mask-entries into per-pair entries + seed rck (tiny) ----
__global__ void vq_expand(const int* __restrict__ flist, const unsigned int* __restrict__ fcount,
                          int* __restrict__ flist2, unsigned int* __restrict__ fcount2,
                          unsigned long long* __restrict__ rck)
{
    const unsigned int cnt = *fcount;
    for (unsigned int i = blockIdx.x * 256 + threadIdx.x; i < cnt; i += gridDim.x * 256) {
        int e = flist[i];
        int row  = e & 0x1FFFF;
        int mask = ((unsigned int)e) >> 17;
        rck[row] = ~0ull;
        while (mask) {
            int c = __ffs(mask) - 1;
            mask &= mask - 1;
            unsigned int p = atomicAdd(fcount2, 1u);
            flist2[p] = row | (c << 17);
        }
    }
}

// ---- exact np-f32-chain recheck: ONE WAVE PER (row, block) PAIR, no barriers. ----
__global__ __launch_bounds__(256)
void vq_recheck_pairs(const float* __restrict__ z, const float* __restrict__ cbT,
                      const float* __restrict__ cnorm, const int* __restrict__ flist2,
                      const unsigned int* __restrict__ fcount2,
                      unsigned long long* __restrict__ rck)
{
    const int tid  = threadIdx.x;
    const int wid  = tid >> 6;
    const int lane = tid & 63;
    const unsigned int cnt = *fcount2;

    for (unsigned int p = blockIdx.x * 4 + wid; p < cnt; p += gridDim.x * 4) {
        const int e   = flist2[p];
        const int row = e & 0x1FFFF;
        const int blk = ((unsigned int)e) >> 17;
        const float* zr = z + (size_t)row * DIM;

        float4 zv = ((const float4*)zr)[lane];
        double s = 0.0;
        s = fma((double)zv.x, (double)zv.x, s);
        s = fma((double)zv.y, (double)zv.y, s);
        s = fma((double)zv.z, (double)zv.z, s);
        s = fma((double)zv.w, (double)zv.w, s);
        #pragma unroll
        for (int off = 32; off > 0; off >>= 1) s += __shfl_xor(s, off);
        const float zz = (float)s;

        const int c0 = blk * 128 + lane;        // lane's two codes (c0 < c0+64)
        float e0 = 0.0f, e1 = 0.0f;
        #pragma unroll 8
        for (int d4 = 0; d4 < 64; ++d4) {       // strict sequential k = 0..255
            float4 zq = ((const float4*)zr)[d4];             // wave-uniform, L1-hot
            float4 a  = ((const float4*)cbT)[d4 * KC + c0];  // coalesced over lanes
            float4 b  = ((const float4*)cbT)[d4 * KC + c0 + 64];
            e0 = fmaf(zq.x, a.x, e0); e0 = fmaf(zq.y, a.y, e0);
            e0 = fmaf(zq.z, a.z, e0); e0 = fmaf(zq.w, a.w, e0);
            e1 = fmaf(zq.x, b.x, e1); e1 = fmaf(zq.y, b.y, e1);
            e1 = fmaf(zq.z, b.z, e1); e1 = fmaf(zq.w, b.w, e1);
        }
        const float dq0 = fmaf(e0, -2.0f, zz + cnorm[c0]);       // fl(fl(zz+cc) - fl(2e))
        const float dq1 = fmaf(e1, -2.0f, zz + cnorm[c0 + 64]);
        unsigned long long k0 = ((unsigned long long)__float_as_uint(dq0) << 32) | (unsigned int)c0;
        unsigned long long k1 = ((unsigned long long)__float_as_uint(dq1) << 32) | (unsigned int)(c0 + 64);
        unsigned long long k = k0 < k1 ? k0 : k1;
        #pragma unroll
        for (int off = 32; off > 0; off >>= 1) {
            unsigned long long o = __shfl_xor(k, off);
            k = o < k ? o : k;
        }
        if (lane == 0) atomicMin(&rck[row], k);
    }
}

// ---- fixup: one wave per pair (duplicates idempotent): final idx + z_st row rewrite
__global__ __launch_bounds__(256)
void vq_fixup(const float* __restrict__ z, const float* __restrict__ cb,
              const int* __restrict__ flist2, const unsigned int* __restrict__ fcount2,
              const unsigned long long* __restrict__ rck,
              float* __restrict__ out, float* __restrict__ out_idx)
{
    const int tid  = threadIdx.x;
    const int wid  = tid >> 6;
    const int lane = tid & 63;
    const unsigned int cnt = *fcount2;

    for (unsigned int p = blockIdx.x * 4 + wid; p < cnt; p += gridDim.x * 4) {
        const int row  = flist2[p] & 0x1FFFF;
        const int code = (int)(unsigned int)rck[row];   // low 32 bits = winning code
        float4 zv = ((const float4*)z)[(size_t)row * 64 + lane];
        float4 cv = ((const float4*)cb)[(size_t)code * 64 + lane];
        float4 o;
        o.x = zv.x + (cv.x - zv.x);
        o.y = zv.y + (cv.y - zv.y);
        o.z = zv.z + (cv.z - zv.z);
        o.w = zv.w + (cv.w - zv.w);
        ((float4*)out)[(size_t)row * 64 + lane] = o;
        if (lane == 0) out_idx[row] = (float)code;
    }
}

__global__ void vq_loss_final(const double* __restrict__ lparts, float* __restrict__ out_loss) {
    __shared__ double s[256];
    const int tid = threadIdx.x;
    double a = 0.0;
    for (int i = tid; i < NBLK; i += 256) a += lparts[i];
    s[tid] = a;
    __syncthreads();
    for (int sft = 128; sft > 0; sft >>= 1) {
        if (tid < sft) s[tid] += s[tid + sft];
        __syncthreads();
    }
    if (tid == 0) {
        float mean = (float)(s[0] / (double)((size_t)N_TOK * DIM));
        out_loss[0] = 0.25f * mean + mean;   // commit + codebook, reference op order
    }
}

extern "C" void kernel_launch(void* const* d_in, const int* in_sizes, int n_in,
                              void* d_out, int out_size, void* d_ws, size_t ws_size,
                              hipStream_t stream) {
    const float* z  = (const float*)d_in[0];
    const float* cb = (const float*)d_in[1];
    float* out = (float*)d_out;
    char* ws = (char*)d_ws;

    unsigned short*     cb16    = (unsigned short*)(ws);
    float*              cnorm   = (float*)(ws + 524288);
    float*              cbT     = (float*)(ws + 528384);
    unsigned int*       fcounts = (unsigned int*)(ws + 1576960);   // [0]=rows, [1]=pairs
    int*                flist   = (int*)(ws + 1577024);
    int*                flist2  = (int*)(ws + 2101312);
    unsigned long long* rck     = (unsigned long long*)(ws + 6295616);
    double*             lparts  = (double*)(ws + 7344192);

    float* out_idx  = out + (size_t)N_TOK * DIM;
    float* out_loss = out_idx + N_TOK;

    vq_prep_cb<<<KC / 4, 256, 0, stream>>>(cb, cb16, cnorm, cbT, fcounts);
    vq_scores_fused<<<NBLK, 256, 0, stream>>>(z, cb16, cb, cnorm, out, out_idx,
                                              flist, fcounts, lparts);
    vq_expand<<<64, 256, 0, stream>>>(flist, fcounts, flist2, fcounts + 1, rck);
    vq_recheck_pairs<<<2048, 256, 0, stream>>>(z, cbT, cnorm, flist2, fcounts + 1, rck);
    vq_fixup<<<1024, 256, 0, stream>>>(z, cb, flist2, fcounts + 1, rck, out, out_idx);
    vq_loss_final<<<1, 256, 0, stream>>>(lparts, out_loss);
}